// Round 4
// baseline (10797.663 us; speedup 1.0000x reference)
//
#include <hip/hip_runtime.h>
#include <hip/hip_bf16.h>
#include <math.h>

#define NPTS 4096
#define DINF 26

typedef float f32x4v __attribute__((ext_vector_type(4)));
typedef __bf16 bf16x8v __attribute__((ext_vector_type(8)));

__device__ __forceinline__ float ldb(const float* p, int i){ return p[i]; }
__device__ __forceinline__ float lk(float v){ return v >= 0.0f ? v : 0.2f*v; }
__device__ __forceinline__ float wsum64(float v){
#pragma unroll
  for(int o=32;o>0;o>>=1) v += __shfl_down(v,o);
  return v;
}
__device__ __forceinline__ unsigned short f2bf(float f){
  return __builtin_bit_cast(unsigned short, __float2bfloat16(f));
}
__device__ __forceinline__ float bf2f(unsigned short u){
  return __bfloat162float(__builtin_bit_cast(__hip_bfloat16, u));
}
__device__ __forceinline__ void tangent(float nx,float ny,float nz,float* t1,float* t2){
  float s = (nz >= 0.0f) ? 1.0f : -1.0f;
  float a = -1.0f/(s+nz);
  float b = nx*ny*a;
  t1[0]=1.0f+s*nx*nx*a; t1[1]=s*b; t1[2]=-s*nx;
  t2[0]=b; t2[1]=s+ny*ny*a; t2[2]=-ny;
}

// ---- k0 ----
__global__ __launch_bounds__(256) void k0_convert(const float* __restrict__ verts,
                                                  const float* __restrict__ vnorm,
                                                  const float* __restrict__ x,
                                                  float* __restrict__ vertsF,
                                                  float* __restrict__ nF,
                                                  float* __restrict__ pF,
                                                  float* __restrict__ xfF){
  int i = blockIdx.x*blockDim.x + threadIdx.x;
  if(i >= NPTS) return;
#pragma unroll
  for(int d=0;d<3;d++){
    float v = verts[i*3+d];
    vertsF[i*3+d]=v;
    pF[i*3+d]=v*(1.0f/9.0f);
    nF[i*3+d]=vnorm[i*3+d];
  }
#pragma unroll
  for(int c=0;c<16;c++) xfF[i*DINF+c]=x[i*16+c];
}

// ---- k1 ----
__global__ __launch_bounds__(256) void k1_pass1(const float* __restrict__ vertsF,
                                                const float* __restrict__ nF,
                                                float* __restrict__ sc){
  const float inv2s2[5] = {0.5f, 0.125f, 1.0f/18.0f, 0.02f, 0.005f};
  int lane = threadIdx.x & 63;
  int i = blockIdx.x*4 + (threadIdx.x>>6);
  float vix=vertsF[i*3+0], viy=vertsF[i*3+1], viz=vertsF[i*3+2];
  float acc[5][13];
#pragma unroll
  for(int s=0;s<5;s++)
#pragma unroll
    for(int k=0;k<13;k++) acc[s][k]=0.0f;
#pragma unroll 1
  for(int j=lane;j<NPTS;j+=64){
    float vx=vertsF[j*3+0], vy=vertsF[j*3+1], vz=vertsF[j*3+2];
    float nx=nF[j*3+0], ny=nF[j*3+1], nz=nF[j*3+2];
    float dx=vx-vix, dy=vy-viy, dz=vz-viz;
    float d2=dx*dx+dy*dy+dz*dz;
    float x0=vx*vx, x1=vx*vy, x2=vx*vz, x3=vy*vy, x4=vy*vz, x5=vz*vz;
#pragma unroll
    for(int s=0;s<5;s++){
      float w=__expf(-d2*inv2s2[s]);
      acc[s][0]+=w;
      acc[s][1]+=w*vx; acc[s][2]+=w*vy; acc[s][3]+=w*vz;
      acc[s][4]+=w*x0; acc[s][5]+=w*x1; acc[s][6]+=w*x2;
      acc[s][7]+=w*x3; acc[s][8]+=w*x4; acc[s][9]+=w*x5;
      acc[s][10]+=w*nx; acc[s][11]+=w*ny; acc[s][12]+=w*nz;
    }
  }
#pragma unroll
  for(int s=0;s<5;s++)
#pragma unroll
    for(int k=0;k<13;k++) acc[s][k]=wsum64(acc[s][k]);
  if(lane==0){
#pragma unroll
    for(int s=0;s<5;s++){
      float* base = sc + (size_t)s*13*NPTS;
      base[i]=acc[s][0];
      base[NPTS+i*3+0]=acc[s][1]; base[NPTS+i*3+1]=acc[s][2]; base[NPTS+i*3+2]=acc[s][3];
#pragma unroll
      for(int k=0;k<6;k++) base[4*NPTS+i*6+k]=acc[s][4+k];
      float ux=acc[s][10], uy=acc[s][11], uz=acc[s][12];
      float nn=fmaxf(sqrtf(ux*ux+uy*uy+uz*uz), 1e-12f);
      base[10*NPTS+i*3+0]=ux/nn; base[10*NPTS+i*3+1]=uy/nn; base[10*NPTS+i*3+2]=uz/nn;
    }
  }
}

// ---- k2 ----
__global__ __launch_bounds__(256) void k2_pass2(const float* __restrict__ vertsF,
                                                const float* __restrict__ sc,
                                                float* __restrict__ xfF){
  const float inv2s2[5] = {0.5f, 0.125f, 1.0f/18.0f, 0.02f, 0.005f};
  int lane = threadIdx.x & 63;
  int i = blockIdx.x*4 + (threadIdx.x>>6);
  float vix=vertsF[i*3+0], viy=vertsF[i*3+1], viz=vertsF[i*3+2];
  float acc[5][12];
#pragma unroll
  for(int s=0;s<5;s++)
#pragma unroll
    for(int k=0;k<12;k++) acc[s][k]=0.0f;
#pragma unroll 1
  for(int j=lane;j<NPTS;j+=64){
    float vx=vertsF[j*3+0], vy=vertsF[j*3+1], vz=vertsF[j*3+2];
    float dx=vx-vix, dy=vy-viy, dz=vz-viz;
    float d2=dx*dx+dy*dy+dz*dz;
#pragma unroll
    for(int s=0;s<5;s++){
      const float* nsb = sc + (size_t)s*13*NPTS + 10*NPTS;
      float nsx=nsb[j*3+0], nsy=nsb[j*3+1], nsz=nsb[j*3+2];
      float w=__expf(-d2*inv2s2[s]);
      acc[s][0]+=w*nsx; acc[s][1]+=w*nsy; acc[s][2]+=w*nsz;
      float wx=w*vx, wy=w*vy, wz=w*vz;
      acc[s][3]+=wx*nsx; acc[s][4]+=wx*nsy; acc[s][5]+=wx*nsz;
      acc[s][6]+=wy*nsx; acc[s][7]+=wy*nsy; acc[s][8]+=wy*nsz;
      acc[s][9]+=wz*nsx; acc[s][10]+=wz*nsy; acc[s][11]+=wz*nsz;
    }
  }
#pragma unroll
  for(int s=0;s<5;s++)
#pragma unroll
    for(int k=0;k<12;k++) acc[s][k]=wsum64(acc[s][k]);
  if(lane==0){
    float v[3]={vix,viy,viz};
#pragma unroll
    for(int s=0;s<5;s++){
      const float* base = sc + (size_t)s*13*NPTS;
      float s0=base[i];
      float sx[3]={base[NPTS+i*3+0], base[NPTS+i*3+1], base[NPTS+i*3+2]};
      float sxx6[6];
#pragma unroll
      for(int k=0;k<6;k++) sxx6[k]=base[4*NPTS+i*6+k];
      float nsi[3]={base[10*NPTS+i*3+0], base[10*NPTS+i*3+1], base[10*NPTS+i*3+2]};
      float sn[3]={acc[s][0],acc[s][1],acc[s][2]};
      float sxn[3][3];
#pragma unroll
      for(int a=0;a<3;a++)
#pragma unroll
        for(int b=0;b<3;b++) sxn[a][b]=acc[s][3+a*3+b];
      const int m6[3][3]={{0,1,2},{1,3,4},{2,4,5}};
      float cxx[3][3], cxn[3][3];
#pragma unroll
      for(int a=0;a<3;a++)
#pragma unroll
        for(int b=0;b<3;b++){
          cxx[a][b]=sxx6[m6[a][b]] - v[a]*sx[b] - sx[a]*v[b] + s0*v[a]*v[b];
          cxn[a][b]=sxn[a][b]    - v[a]*sn[b] - sx[a]*nsi[b] + s0*v[a]*nsi[b];
        }
      float t1[3],t2[3];
      tangent(nsi[0],nsi[1],nsi[2],t1,t2);
      float ppt[2][2], pqt[2][2];
#pragma unroll
      for(int k=0;k<2;k++){
        const float* tk = (k==0)?t1:t2;
#pragma unroll
        for(int l=0;l<2;l++){
          const float* tl = (l==0)?t1:t2;
          float accx=0.0f, accn=0.0f;
#pragma unroll
          for(int a=0;a<3;a++)
#pragma unroll
            for(int b=0;b<3;b++){
              accx += tk[a]*cxx[a][b]*tl[b];
              accn += tk[a]*cxn[a][b]*tl[b];
            }
          ppt[k][l]=accx + ((k==l)?0.01f:0.0f);
          pqt[k][l]=accn;
        }
      }
      float det = ppt[0][0]*ppt[1][1]-ppt[0][1]*ppt[1][0];
      float id = 1.0f/det;
      float S00=( ppt[1][1]*pqt[0][0]-ppt[0][1]*pqt[1][0])*id;
      float S01=( ppt[1][1]*pqt[0][1]-ppt[0][1]*pqt[1][1])*id;
      float S10=(-ppt[1][0]*pqt[0][0]+ppt[0][0]*pqt[1][0])*id;
      float S11=(-ppt[1][0]*pqt[0][1]+ppt[0][0]*pqt[1][1])*id;
      float f0=fminf(fmaxf(S00+S11,-1.0f),1.0f);
      float f1=fminf(fmaxf(S00*S11-S01*S10,-1.0f),1.0f);
      xfF[i*DINF+16+2*s]=f0;
      xfF[i*DINF+17+2*s]=f1;
    }
  }
}

// ---- k3 ----
__global__ __launch_bounds__(256) void k3_mlps(const float* __restrict__ xfF,
    const float* os_w1, const float* os_b1, const float* os_w2, const float* os_b2,
    const float* ni_w1, const float* ni_b1, const float* ni_w2, const float* ni_b2,
    float* __restrict__ wOS, float* __restrict__ hPre, float* __restrict__ stats){
  int i = blockIdx.x*256 + threadIdx.x;
  int lane = threadIdx.x & 63;
  float xf[DINF];
#pragma unroll
  for(int k=0;k<DINF;k++) xf[k]=xfF[i*DINF+k];
  float h1[16];
#pragma unroll
  for(int o=0;o<16;o++){
    float t=ldb(os_b1,o);
#pragma unroll
    for(int k=0;k<DINF;k++) t += xf[k]*ldb(os_w1,o*DINF+k);
    h1[o]=lk(t);
  }
  float w=ldb(os_b2,0);
#pragma unroll
  for(int o=0;o<16;o++) w += h1[o]*ldb(os_w2,o);
  wOS[i]=w;
#pragma unroll
  for(int o=0;o<16;o++){
    float t=ldb(ni_b1,o);
#pragma unroll
    for(int k=0;k<DINF;k++) t += xf[k]*ldb(ni_w1,o*DINF+k);
    h1[o]=lk(t);
  }
  float h2[16];
#pragma unroll
  for(int o=0;o<16;o++){
    float t=ldb(ni_b2,o);
#pragma unroll
    for(int k=0;k<16;k++) t += h1[k]*ldb(ni_w2,o*16+k);
    h2[o]=lk(t);
    hPre[i*16+o]=h2[o];
  }
  float gs[4]={0,0,0,0}, gq[4]={0,0,0,0};
#pragma unroll
  for(int c=0;c<16;c++){ gs[c>>2]+=h2[c]; gq[c>>2]+=h2[c]*h2[c]; }
  __shared__ float ls[8];
  if(threadIdx.x<8) ls[threadIdx.x]=0.0f;
  __syncthreads();
#pragma unroll
  for(int g=0;g<4;g++){ gs[g]=wsum64(gs[g]); gq[g]=wsum64(gq[g]); }
  if(lane==0){
#pragma unroll
    for(int g=0;g<4;g++){ atomicAdd(&ls[2*g],gs[g]); atomicAdd(&ls[2*g+1],gq[g]); }
  }
  __syncthreads();
  if(threadIdx.x<8) atomicAdd(&stats[threadIdx.x], ls[threadIdx.x]);
}

// ---- k3c: GN -> hF + bf16 transposed hTb[16][4096] ----
__global__ __launch_bounds__(256) void k3c_gn(const float* __restrict__ hPre,
                                              const float* __restrict__ stats,
                                              const float* gw, const float* gb,
                                              float* __restrict__ hF,
                                              unsigned short* __restrict__ hTb){
  int i = blockIdx.x*256 + threadIdx.x;
  float m[4], r[4];
#pragma unroll
  for(int g=0;g<4;g++){
    float mean = stats[2*g]*(1.0f/(4.0f*NPTS));
    float var  = stats[2*g+1]*(1.0f/(4.0f*NPTS)) - mean*mean;
    m[g]=mean; r[g]=1.0f/sqrtf(var+1e-5f);
  }
#pragma unroll
  for(int c=0;c<16;c++){
    int g=c>>2;
    float v=(hPre[i*16+c]-m[g])*r[g]*ldb(gw,c)+ldb(gb,c);
    hF[i*16+c]=v;
    hTb[c*NPTS+i]=f2bf(v);
  }
}

// ---- k4 (R2 form) ----
__global__ __launch_bounds__(256) void k4_ov(const float* __restrict__ pF,
                                             const float* __restrict__ nF,
                                             const float* __restrict__ wOS,
                                             float* __restrict__ nuvF){
  int lane = threadIdx.x & 63;
  int i = blockIdx.x*4 + (threadIdx.x>>6);
  float pix=pF[i*3+0], piy=pF[i*3+1], piz=pF[i*3+2];
  float nix=nF[i*3+0], niy=nF[i*3+1], niz=nF[i*3+2];
  float a0=0,a1=0,a2=0,a3=0;
#pragma unroll 1
  for(int j=lane;j<NPTS;j+=64){
    float px=pF[j*3+0], py=pF[j*3+1], pz=pF[j*3+2];
    float nx=nF[j*3+0], ny=nF[j*3+1], nz=nF[j*3+2];
    float wj=wOS[j];
    float dx=px-pix, dy=py-piy, dz=pz-piz;
    float d2=dx*dx+dy*dy+dz*dz;
    float f=2.0f-(nx*nix+ny*niy+nz*niz);
    float Wv=__expf(-d2*f*f);
    float Ww=Wv*wj;
    a0+=Ww*px; a1+=Ww*py; a2+=Ww*pz; a3+=Ww;
  }
  a0=wsum64(a0); a1=wsum64(a1); a2=wsum64(a2); a3=wsum64(a3);
  if(lane==0){
    float o0=a0-a3*pix, o1=a1-a3*piy, o2=a2-a3*piz;
    float t1[3],t2[3];
    tangent(nix,niy,niz,t1,t2);
    float ov0=t1[0]*o0+t1[1]*o1+t1[2]*o2+1e-5f;
    float ov1=t2[0]*o0+t2[1]*o1+t2[2]*o2+1e-5f;
    float inv=1.0f/sqrtf(ov0*ov0+ov1*ov1);
    float ex=ov0*inv, ey=ov1*inv;
    nuvF[i*9+0]=nix; nuvF[i*9+1]=niy; nuvF[i*9+2]=niz;
    nuvF[i*9+3]= ex*t1[0]+ey*t2[0]; nuvF[i*9+4]= ex*t1[1]+ey*t2[1]; nuvF[i*9+5]= ex*t1[2]+ey*t2[2];
    nuvF[i*9+6]=-ey*t1[0]+ex*t2[0]; nuvF[i*9+7]=-ey*t1[1]+ex*t2[1]; nuvF[i*9+8]=-ey*t1[2]+ex*t2[2];
  }
}

// ---- k5m: MFMA conv -> xiM (scratch) + probe dumps for i=0 ----
__global__ __launch_bounds__(256) void k5m(const float* __restrict__ pF,
                                           const float* __restrict__ nF,
                                           const float* __restrict__ nuvF,
                                           const unsigned short* __restrict__ hTb,
                                           const float* cv_a1, const float* cv_b1,
                                           const float* cv_a2, const float* cv_b2,
                                           float* __restrict__ xiM,
                                           float* __restrict__ Mdump,
                                           float* __restrict__ Mdump2){
  __shared__ unsigned short zs[4][64][20];
  int lane = threadIdx.x & 63;
  int w = threadIdx.x >> 6;
  int i = blockIdx.x*4 + w;
  int c16 = lane & 15, q = lane >> 4;
  // zero unused columns once (never written in loop)
#pragma unroll
  for(int c=9;c<20;c++) zs[w][lane][c]=0;
  float pix=pF[i*3+0], piy=pF[i*3+1], piz=pF[i*3+2];
  float nu[9];
#pragma unroll
  for(int k=0;k<9;k++) nu[k]=nuvF[i*9+k];
  float a1w[8][3], b1w[8];
#pragma unroll
  for(int c=0;c<8;c++){
    a1w[c][0]=cv_a1[c*3+0]; a1w[c][1]=cv_a1[c*3+1]; a1w[c][2]=cv_a1[c*3+2];
    b1w[c]=cv_b1[c];
  }
  const unsigned short* hrow = hTb + c16*NPTS;
  f32x4v acc = {0.0f,0.0f,0.0f,0.0f};
  f32x4v accI = {0.0f,0.0f,0.0f,0.0f};
  bf16x8v idA;
#pragma unroll
  for(int t=0;t<8;t++)
    idA[t] = __builtin_bit_cast(__bf16, (unsigned short)((c16 == q*8+t) ? 0x3F80 : 0));
  bool probe = (blockIdx.x==0) && (w==0);

#pragma unroll 1
  for(int jb=0; jb<NPTS; jb+=64){
    int j = jb + lane;
    float px=pF[j*3+0], py=pF[j*3+1], pz=pF[j*3+2];
    float nx=nF[j*3+0], ny=nF[j*3+1], nz=nF[j*3+2];
    float dx=px-pix, dy=py-piy, dz=pz-piz;
    float d2=dx*dx+dy*dy+dz*dz;
    float f=2.0f-(nx*nu[0]+ny*nu[1]+nz*nu[2]);
    float win=__expf(-d2*f*f);
    float X0=nu[0]*dx+nu[1]*dy+nu[2]*dz;
    float X1=nu[3]*dx+nu[4]*dy+nu[5]*dz;
    float X2=nu[6]*dx+nu[7]*dy+nu[8]*dz;
    unsigned short* zrow = &zs[w][lane][0];
#pragma unroll
    for(int c=0;c<8;c++){
      float r=fmaf(X0,a1w[c][0],fmaf(X1,a1w[c][1],fmaf(X2,a1w[c][2],b1w[c])));
      zrow[c]=f2bf(win*fmaxf(r,0.0f));
    }
    zrow[8]=f2bf(win);
#pragma unroll
    for(int q2=0;q2<2;q2++){
      int jb2 = jb + q2*32;
      bf16x8v bfr;
#pragma unroll
      for(int t=0;t<8;t++){
        unsigned short v = zs[w][q2*32 + q*8 + t][c16];
        bfr[t] = __builtin_bit_cast(__bf16, v);
      }
      if(probe && jb==0 && q2==0)
        accI = __builtin_amdgcn_mfma_f32_16x16x32_bf16(idA, bfr, accI, 0, 0, 0);
      bf16x8v afr = *(const bf16x8v*)(hrow + jb2 + q*8);
      acc = __builtin_amdgcn_mfma_f32_16x16x32_bf16(afr, bfr, acc, 0, 0, 0);
    }
  }
#pragma unroll
  for(int r=0;r<4;r++){
    int h = q*4 + r;
    float coef = (c16<8) ? cv_a2[h*8+c16] : ((c16==8) ? cv_b2[h] : 0.0f);
    float v = acc[r]*coef;
#pragma unroll
    for(int o=1;o<16;o<<=1) v += __shfl_xor(v,o);
    if(c16==0) xiM[i*16+h]=v;
  }
  if(probe){
#pragma unroll
    for(int r=0;r<4;r++){
      Mdump[lane*4+r]=acc[r];
      Mdump2[lane*4+r]=accI[r];
    }
  }
}

// ---- k5s: scalar conv (R2, known good) -> xiF ----
__global__ __launch_bounds__(256,2) void k5s(const float* __restrict__ pF,
                                             const float* __restrict__ nF,
                                             const float* __restrict__ nuvF,
                                             const float* __restrict__ hF,
                                             const float* cv_a1, const float* cv_b1,
                                             const float* cv_a2, const float* cv_b2,
                                             float* __restrict__ xiF){
  int lane = threadIdx.x & 63;
  int i = blockIdx.x*4 + (threadIdx.x>>6);
  float pix=pF[i*3+0], piy=pF[i*3+1], piz=pF[i*3+2];
  float nu[9];
#pragma unroll
  for(int k=0;k<9;k++) nu[k]=nuvF[i*9+k];
  float a1w[8][3], b1w[8];
#pragma unroll
  for(int c=0;c<8;c++){
    a1w[c][0]=ldb(cv_a1,c*3+0); a1w[c][1]=ldb(cv_a1,c*3+1); a1w[c][2]=ldb(cv_a1,c*3+2);
    b1w[c]=ldb(cv_b1,c);
  }
  float G[16][8], gg[16];
#pragma unroll
  for(int h=0;h<16;h++){
    gg[h]=0.0f;
#pragma unroll
    for(int c=0;c<8;c++) G[h][c]=0.0f;
  }
#pragma unroll 1
  for(int j=lane;j<NPTS;j+=64){
    float px=pF[j*3+0], py=pF[j*3+1], pz=pF[j*3+2];
    float nx=nF[j*3+0], ny=nF[j*3+1], nz=nF[j*3+2];
    float dx=px-pix, dy=py-piy, dz=pz-piz;
    float d2=dx*dx+dy*dy+dz*dz;
    float f=2.0f-(nx*nu[0]+ny*nu[1]+nz*nu[2]);
    float win=__expf(-d2*f*f);
    float X0=nu[0]*dx+nu[1]*dy+nu[2]*dz;
    float X1=nu[3]*dx+nu[4]*dy+nu[5]*dz;
    float X2=nu[6]*dx+nu[7]*dy+nu[8]*dz;
    float wr[8];
#pragma unroll
    for(int c=0;c<8;c++){
      float r=X0*a1w[c][0]+X1*a1w[c][1]+X2*a1w[c][2]+b1w[c];
      wr[c]=win*fmaxf(r,0.0f);
    }
    const float4* h4=(const float4*)(hF+j*16);
    float4 hA=h4[0], hB=h4[1], hC=h4[2], hD=h4[3];
    float hv[16]={hA.x,hA.y,hA.z,hA.w, hB.x,hB.y,hB.z,hB.w,
                  hC.x,hC.y,hC.z,hC.w, hD.x,hD.y,hD.z,hD.w};
#pragma unroll
    for(int h=0;h<16;h++){
      gg[h]+=win*hv[h];
#pragma unroll
      for(int c=0;c<8;c++) G[h][c]+=hv[h]*wr[c];
    }
  }
#pragma unroll
  for(int h=0;h<16;h++){
    float xi=gg[h]*ldb(cv_b2,h);
#pragma unroll
    for(int c=0;c<8;c++) xi += G[h][c]*ldb(cv_a2,h*8+c);
    xi=wsum64(xi);
    if(lane==0) xiF[i*16+h]=xi;
  }
}

// ---- kdiag: localize the MFMA discrepancy; encode verdict in duration ----
__global__ __launch_bounds__(64) void kdiag(const float* __restrict__ pF,
    const float* __restrict__ nF, const float* __restrict__ nuvF,
    const unsigned short* __restrict__ hTb, const float* __restrict__ hF,
    const float* cv_a1, const float* cv_b1, const float* cv_a2, const float* cv_b2,
    const float* __restrict__ Mdump, const float* __restrict__ Mdump2,
    const float* __restrict__ xiM, const float* __restrict__ xiF,
    float* __restrict__ dbg){
  int lane = threadIdx.x;
  float pix=pF[0], piy=pF[1], piz=pF[2];
  float nu[9];
#pragma unroll
  for(int k=0;k<9;k++) nu[k]=nuvF[k];
  float a1w[8][3], b1w[8];
#pragma unroll
  for(int c=0;c<8;c++){
    a1w[c][0]=cv_a1[c*3+0]; a1w[c][1]=cv_a1[c*3+1]; a1w[c][2]=cv_a1[c*3+2];
    b1w[c]=cv_b1[c];
  }
  float M[16][9];
#pragma unroll
  for(int h=0;h<16;h++)
#pragma unroll
    for(int c=0;c<9;c++) M[h][c]=0.0f;
  __shared__ float z0s[32][9];
#pragma unroll 1
  for(int j=lane;j<NPTS;j+=64){
    float px=pF[j*3+0], py=pF[j*3+1], pz=pF[j*3+2];
    float nx=nF[j*3+0], ny=nF[j*3+1], nz=nF[j*3+2];
    float dx=px-pix, dy=py-piy, dz=pz-piz;
    float d2=dx*dx+dy*dy+dz*dz;
    float f=2.0f-(nx*nu[0]+ny*nu[1]+nz*nu[2]);
    float win=__expf(-d2*f*f);
    float X0=nu[0]*dx+nu[1]*dy+nu[2]*dz;
    float X1=nu[3]*dx+nu[4]*dy+nu[5]*dz;
    float X2=nu[6]*dx+nu[7]*dy+nu[8]*dz;
    float zq[9];
#pragma unroll
    for(int c=0;c<8;c++){
      float r=fmaf(X0,a1w[c][0],fmaf(X1,a1w[c][1],fmaf(X2,a1w[c][2],b1w[c])));
      zq[c]=bf2f(f2bf(win*fmaxf(r,0.0f)));
    }
    zq[8]=bf2f(f2bf(win));
    if(j<32){
#pragma unroll
      for(int c=0;c<9;c++) z0s[j][c]=zq[c];
    }
#pragma unroll
    for(int h=0;h<16;h++){
      float hq=bf2f(hTb[h*NPTS+j]);
#pragma unroll
      for(int c=0;c<9;c++) M[h][c]+=hq*zq[c];
    }
  }
#pragma unroll
  for(int h=0;h<16;h++)
#pragma unroll
    for(int c=0;c<9;c++) M[h][c]=wsum64(M[h][c]);
  // global xiM vs xiF max-diff
  float xid=0.0f;
  for(int n=lane;n<16*NPTS;n+=64) xid=fmaxf(xid, fabsf(xiM[n]-xiF[n]));
#pragma unroll
  for(int o=32;o>0;o>>=1) xid=fmaxf(xid, __shfl_down(xid,o));
  // hTb vs hF
  float hd=0.0f;
  for(int n=lane;n<16*NPTS;n+=64){
    int pt=n>>4, ch=n&15;
    hd=fmaxf(hd, fabsf(bf2f(hTb[ch*NPTS+pt]) - hF[n]));
  }
#pragma unroll
  for(int o=32;o>0;o>>=1) hd=fmaxf(hd, __shfl_down(hd,o));

  if(lane==0){
    int binA=4, binB=4;
    for(int m=0;m<4;m++){
      float eA=0.0f, eB=0.0f;
      for(int L=0;L<64;L++){
        for(int r=0;r<4;r++){
          int a,b;
          if(m==0){a=(L>>4)*4+r; b=L&15;}
          else if(m==1){a=L&15; b=(L>>4)*4+r;}
          else if(m==2){a=(L>>4)+4*r; b=L&15;}
          else {a=L&15; b=(L>>4)+4*r;}
          float tvA = (b<9)? M[a][b] : 0.0f;
          float tvB = (b<9)? z0s[a][b] : 0.0f;
          eA=fmaxf(eA, fabsf(Mdump[L*4+r]-tvA)/(1.0f+fabsf(tvA)));
          eB=fmaxf(eB, fabsf(Mdump2[L*4+r]-tvB)/(1.0f+fabsf(tvB)));
        }
      }
      if(eA<0.02f && binA==4) binA=m;
      if(eB<0.02f && binB==4) binB=m;
    }
    // epilogue check for i=0
    float xe=0.0f;
    for(int h=0;h<16;h++){
      float v=M[h][8]*cv_b2[h];
      for(int c=0;c<8;c++) v+=M[h][c]*cv_a2[h*8+c];
      xe=fmaxf(xe, fabsf(v-xiM[h])/(1.0f+fabsf(v)));
    }
    int xibit=(xid>0.05f)?1:0;
    int hbit=(hd>0.02f)?1:0;
    int dbit=(xe>0.02f)?1:0;
    dbg[0]=(float)binA; dbg[1]=(float)binB; dbg[2]=xid; dbg[3]=hd; dbg[4]=xe;
    long long u = 1 + binA + 8*(long long)binB + 64*(long long)xibit
                  + 128*(long long)hbit + 256*(long long)dbit;
    long long tgt = u * 15000;  // ~150us units at 100 MHz realtime clock
    long long t0 = __builtin_amdgcn_s_memrealtime();
    while(__builtin_amdgcn_s_memrealtime() - t0 < tgt) {}
  }
}

// ---- k6a ----
__global__ __launch_bounds__(256) void k6a(const float* __restrict__ xiF,
    const float* no_w1, const float* no_b1, const float* no_w2, const float* no_b2,
    float* __restrict__ tF, float* __restrict__ stats2){
  int i = blockIdx.x*256 + threadIdx.x;
  int lane = threadIdx.x & 63;
  float xi[16];
#pragma unroll
  for(int k=0;k<16;k++) xi[k]=xiF[i*16+k];
  float t1[16];
#pragma unroll
  for(int o=0;o<16;o++){
    float t=ldb(no_b1,o);
#pragma unroll
    for(int k=0;k<16;k++) t += xi[k]*ldb(no_w1,o*16+k);
    t1[o]=lk(t);
  }
  float t2[16];
#pragma unroll
  for(int o=0;o<16;o++){
    float t=ldb(no_b2,o);
#pragma unroll
    for(int k=0;k<16;k++) t += t1[k]*ldb(no_w2,o*16+k);
    t2[o]=lk(t);
    tF[i*16+o]=t2[o];
  }
  float gs[4]={0,0,0,0}, gq[4]={0,0,0,0};
#pragma unroll
  for(int c=0;c<16;c++){ gs[c>>2]+=t2[c]; gq[c>>2]+=t2[c]*t2[c]; }
  __shared__ float ls[8];
  if(threadIdx.x<8) ls[threadIdx.x]=0.0f;
  __syncthreads();
#pragma unroll
  for(int g=0;g<4;g++){ gs[g]=wsum64(gs[g]); gq[g]=wsum64(gq[g]); }
  if(lane==0){
#pragma unroll
    for(int g=0;g<4;g++){ atomicAdd(&ls[2*g],gs[g]); atomicAdd(&ls[2*g+1],gq[g]); }
  }
  __syncthreads();
  if(threadIdx.x<8) atomicAdd(&stats2[threadIdx.x], ls[threadIdx.x]);
}

// ---- k6c ----
__global__ __launch_bounds__(256) void k6c(const float* __restrict__ tF,
    const float* __restrict__ xfF, const float* __restrict__ stats2,
    const float* gw, const float* gb,
    const float* ll_w1, const float* ll_b1, const float* ll_w2, const float* ll_b2,
    const float* lt_w, const float* lt_b,
    float* __restrict__ out){
  int i = blockIdx.x*256 + threadIdx.x;
  float m[4], r[4];
#pragma unroll
  for(int g=0;g<4;g++){
    float mean = stats2[2*g]*(1.0f/(4.0f*NPTS));
    float var  = stats2[2*g+1]*(1.0f/(4.0f*NPTS)) - mean*mean;
    m[g]=mean; r[g]=1.0f/sqrtf(var+1e-5f);
  }
  float tn[16];
#pragma unroll
  for(int c=0;c<16;c++){
    int g=c>>2;
    tn[c]=(tF[i*16+c]-m[g])*r[g]*ldb(gw,c)+ldb(gb,c);
  }
  float z1[16];
#pragma unroll
  for(int o=0;o<16;o++){
    float t=ldb(ll_b1,o);
#pragma unroll
    for(int k=0;k<16;k++) t += tn[k]*ldb(ll_w1,o*16+k);
    z1[o]=fmaxf(t,0.0f);
  }
  float xf[DINF];
#pragma unroll
  for(int k=0;k<DINF;k++) xf[k]=xfF[i*DINF+k];
#pragma unroll
  for(int o=0;o<16;o++){
    float z=ldb(ll_b2,o);
#pragma unroll
    for(int k=0;k<16;k++) z += z1[k]*ldb(ll_w2,o*16+k);
    float lt=ldb(lt_b,o);
#pragma unroll
    for(int k=0;k<DINF;k++) lt += xf[k]*ldb(lt_w,o*DINF+k);
    out[i*16+o]=z+lt;
  }
}

extern "C" void kernel_launch(void* const* d_in, const int* in_sizes, int n_in,
                              void* d_out, int out_size, void* d_ws, size_t ws_size,
                              hipStream_t stream){
  const float* verts    = (const float*)d_in[0];
  const float* vnormals = (const float*)d_in[1];
  const float* x        = (const float*)d_in[2];
  const float* os_w1    = (const float*)d_in[3];
  const float* os_b1    = (const float*)d_in[4];
  const float* os_w2    = (const float*)d_in[5];
  const float* os_b2    = (const float*)d_in[6];
  const float* ni_w1    = (const float*)d_in[7];
  const float* ni_b1    = (const float*)d_in[8];
  const float* ni_w2    = (const float*)d_in[9];
  const float* ni_b2    = (const float*)d_in[10];
  const float* gn_in_w  = (const float*)d_in[11];
  const float* gn_in_b  = (const float*)d_in[12];
  const float* cv_a1    = (const float*)d_in[13];
  const float* cv_b1    = (const float*)d_in[14];
  const float* cv_a2    = (const float*)d_in[15];
  const float* cv_b2    = (const float*)d_in[16];
  const float* no_w1    = (const float*)d_in[17];
  const float* no_b1    = (const float*)d_in[18];
  const float* no_w2    = (const float*)d_in[19];
  const float* no_b2    = (const float*)d_in[20];
  const float* gn_out_w = (const float*)d_in[21];
  const float* gn_out_b = (const float*)d_in[22];
  const float* ll_w1    = (const float*)d_in[23];
  const float* ll_b1    = (const float*)d_in[24];
  const float* ll_w2    = (const float*)d_in[25];
  const float* ll_b2    = (const float*)d_in[26];
  const float* lt_w     = (const float*)d_in[27];
  const float* lt_b     = (const float*)d_in[28];

  float* W = (float*)d_ws;
  size_t off = 0;
  float* vertsF = W + off; off += (size_t)3*NPTS;
  float* nF     = W + off; off += (size_t)3*NPTS;
  float* pF     = W + off; off += (size_t)3*NPTS;
  float* xfF    = W + off; off += (size_t)DINF*NPTS;
  float* sc     = W + off; off += (size_t)13*NPTS*5;   // reused post-k2 for probes
  float* wOS    = W + off; off += (size_t)NPTS;
  float* hPre   = W + off; off += (size_t)16*NPTS;
  float* hF     = W + off; off += (size_t)16*NPTS;
  float* nuvF   = W + off; off += (size_t)9*NPTS;
  float* xiF    = W + off; off += (size_t)16*NPTS;
  float* tF     = W + off; off += (size_t)16*NPTS;
  float* stats  = W + off; off += 16;
  // probe regions aliased into sc (free after k2 completes)
  unsigned short* hTb = (unsigned short*)sc;        // 16*NPTS bf16 = 8N floats
  float* xiM    = sc + (size_t)8*NPTS;              // 16N floats
  float* Mdump  = sc + (size_t)24*NPTS;             // 256
  float* Mdump2 = Mdump + 256;                      // 256
  float* dbg    = Mdump + 512;                      // 16

  hipMemsetAsync(stats, 0, 16*sizeof(float), stream);

  k0_convert<<<NPTS/256, 256, 0, stream>>>(verts, vnormals, x, vertsF, nF, pF, xfF);
  k1_pass1<<<NPTS/4, 256, 0, stream>>>(vertsF, nF, sc);
  k2_pass2<<<NPTS/4, 256, 0, stream>>>(vertsF, sc, xfF);
  k3_mlps<<<NPTS/256, 256, 0, stream>>>(xfF, os_w1, os_b1, os_w2, os_b2,
                                        ni_w1, ni_b1, ni_w2, ni_b2, wOS, hPre, stats);
  k3c_gn<<<NPTS/256, 256, 0, stream>>>(hPre, stats, gn_in_w, gn_in_b, hF, hTb);
  k4_ov<<<NPTS/4, 256, 0, stream>>>(pF, nF, wOS, nuvF);
  k5m<<<NPTS/4, 256, 0, stream>>>(pF, nF, nuvF, hTb, cv_a1, cv_b1, cv_a2, cv_b2,
                                  xiM, Mdump, Mdump2);
  k5s<<<NPTS/4, 256, 0, stream>>>(pF, nF, nuvF, hF, cv_a1, cv_b1, cv_a2, cv_b2, xiF);
  kdiag<<<1, 64, 0, stream>>>(pF, nF, nuvF, hTb, hF, cv_a1, cv_b1, cv_a2, cv_b2,
                              Mdump, Mdump2, xiM, xiF, dbg);
  k6a<<<NPTS/256, 256, 0, stream>>>(xiF, no_w1, no_b1, no_w2, no_b2, tF, stats+8);
  k6c<<<NPTS/256, 256, 0, stream>>>(tF, xfF, stats+8, gn_out_w, gn_out_b,
                                    ll_w1, ll_b1, ll_w2, ll_b2, lt_w, lt_b, (float*)d_out);
}

// Round 5
// 399.675 us; speedup vs baseline: 27.0161x; 27.0161x over previous
//
#include <hip/hip_runtime.h>
#include <hip/hip_bf16.h>
#include <math.h>

#define NPTS 4096
#define DINF 26

typedef float f32x4v __attribute__((ext_vector_type(4)));
typedef __bf16 bf16x8v __attribute__((ext_vector_type(8)));

__device__ __forceinline__ float ldb(const float* p, int i){ return p[i]; }
__device__ __forceinline__ float lk(float v){ return v >= 0.0f ? v : 0.2f*v; }
__device__ __forceinline__ float wsum64(float v){
#pragma unroll
  for(int o=32;o>0;o>>=1) v += __shfl_down(v,o);
  return v;
}
__device__ __forceinline__ unsigned short f2bf(float f){
  return __builtin_bit_cast(unsigned short, __float2bfloat16(f));
}
__device__ __forceinline__ void tangent(float nx,float ny,float nz,float* t1,float* t2){
  float s = (nz >= 0.0f) ? 1.0f : -1.0f;
  float a = -1.0f/(s+nz);
  float b = nx*ny*a;
  t1[0]=1.0f+s*nx*nx*a; t1[1]=s*b; t1[2]=-s*nx;
  t2[0]=b; t2[1]=s+ny*ny*a; t2[2]=-ny;
}

// ---- k0 ----
__global__ __launch_bounds__(256) void k0_convert(const float* __restrict__ verts,
                                                  const float* __restrict__ vnorm,
                                                  const float* __restrict__ x,
                                                  float* __restrict__ vertsF,
                                                  float* __restrict__ nF,
                                                  float* __restrict__ pF,
                                                  float* __restrict__ xfF){
  int i = blockIdx.x*blockDim.x + threadIdx.x;
  if(i >= NPTS) return;
#pragma unroll
  for(int d=0;d<3;d++){
    float v = verts[i*3+d];
    vertsF[i*3+d]=v;
    pF[i*3+d]=v*(1.0f/9.0f);
    nF[i*3+d]=vnorm[i*3+d];
  }
#pragma unroll
  for(int c=0;c<16;c++) xfF[i*DINF+c]=x[i*16+c];
}

// ---- k1 ----
__global__ __launch_bounds__(256) void k1_pass1(const float* __restrict__ vertsF,
                                                const float* __restrict__ nF,
                                                float* __restrict__ sc){
  const float inv2s2[5] = {0.5f, 0.125f, 1.0f/18.0f, 0.02f, 0.005f};
  int lane = threadIdx.x & 63;
  int i = blockIdx.x*4 + (threadIdx.x>>6);
  float vix=vertsF[i*3+0], viy=vertsF[i*3+1], viz=vertsF[i*3+2];
  float acc[5][13];
#pragma unroll
  for(int s=0;s<5;s++)
#pragma unroll
    for(int k=0;k<13;k++) acc[s][k]=0.0f;
#pragma unroll 1
  for(int j=lane;j<NPTS;j+=64){
    float vx=vertsF[j*3+0], vy=vertsF[j*3+1], vz=vertsF[j*3+2];
    float nx=nF[j*3+0], ny=nF[j*3+1], nz=nF[j*3+2];
    float dx=vx-vix, dy=vy-viy, dz=vz-viz;
    float d2=dx*dx+dy*dy+dz*dz;
    float x0=vx*vx, x1=vx*vy, x2=vx*vz, x3=vy*vy, x4=vy*vz, x5=vz*vz;
#pragma unroll
    for(int s=0;s<5;s++){
      float w=__expf(-d2*inv2s2[s]);
      acc[s][0]+=w;
      acc[s][1]+=w*vx; acc[s][2]+=w*vy; acc[s][3]+=w*vz;
      acc[s][4]+=w*x0; acc[s][5]+=w*x1; acc[s][6]+=w*x2;
      acc[s][7]+=w*x3; acc[s][8]+=w*x4; acc[s][9]+=w*x5;
      acc[s][10]+=w*nx; acc[s][11]+=w*ny; acc[s][12]+=w*nz;
    }
  }
#pragma unroll
  for(int s=0;s<5;s++)
#pragma unroll
    for(int k=0;k<13;k++) acc[s][k]=wsum64(acc[s][k]);
  if(lane==0){
#pragma unroll
    for(int s=0;s<5;s++){
      float* base = sc + (size_t)s*13*NPTS;
      base[i]=acc[s][0];
      base[NPTS+i*3+0]=acc[s][1]; base[NPTS+i*3+1]=acc[s][2]; base[NPTS+i*3+2]=acc[s][3];
#pragma unroll
      for(int k=0;k<6;k++) base[4*NPTS+i*6+k]=acc[s][4+k];
      float ux=acc[s][10], uy=acc[s][11], uz=acc[s][12];
      float nn=fmaxf(sqrtf(ux*ux+uy*uy+uz*uz), 1e-12f);
      base[10*NPTS+i*3+0]=ux/nn; base[10*NPTS+i*3+1]=uy/nn; base[10*NPTS+i*3+2]=uz/nn;
    }
  }
}

// ---- k2 ----
__global__ __launch_bounds__(256) void k2_pass2(const float* __restrict__ vertsF,
                                                const float* __restrict__ sc,
                                                float* __restrict__ xfF){
  const float inv2s2[5] = {0.5f, 0.125f, 1.0f/18.0f, 0.02f, 0.005f};
  int lane = threadIdx.x & 63;
  int i = blockIdx.x*4 + (threadIdx.x>>6);
  float vix=vertsF[i*3+0], viy=vertsF[i*3+1], viz=vertsF[i*3+2];
  float acc[5][12];
#pragma unroll
  for(int s=0;s<5;s++)
#pragma unroll
    for(int k=0;k<12;k++) acc[s][k]=0.0f;
#pragma unroll 1
  for(int j=lane;j<NPTS;j+=64){
    float vx=vertsF[j*3+0], vy=vertsF[j*3+1], vz=vertsF[j*3+2];
    float dx=vx-vix, dy=vy-viy, dz=vz-viz;
    float d2=dx*dx+dy*dy+dz*dz;
#pragma unroll
    for(int s=0;s<5;s++){
      const float* nsb = sc + (size_t)s*13*NPTS + 10*NPTS;
      float nsx=nsb[j*3+0], nsy=nsb[j*3+1], nsz=nsb[j*3+2];
      float w=__expf(-d2*inv2s2[s]);
      acc[s][0]+=w*nsx; acc[s][1]+=w*nsy; acc[s][2]+=w*nsz;
      float wx=w*vx, wy=w*vy, wz=w*vz;
      acc[s][3]+=wx*nsx; acc[s][4]+=wx*nsy; acc[s][5]+=wx*nsz;
      acc[s][6]+=wy*nsx; acc[s][7]+=wy*nsy; acc[s][8]+=wy*nsz;
      acc[s][9]+=wz*nsx; acc[s][10]+=wz*nsy; acc[s][11]+=wz*nsz;
    }
  }
#pragma unroll
  for(int s=0;s<5;s++)
#pragma unroll
    for(int k=0;k<12;k++) acc[s][k]=wsum64(acc[s][k]);
  if(lane==0){
    float v[3]={vix,viy,viz};
#pragma unroll
    for(int s=0;s<5;s++){
      const float* base = sc + (size_t)s*13*NPTS;
      float s0=base[i];
      float sx[3]={base[NPTS+i*3+0], base[NPTS+i*3+1], base[NPTS+i*3+2]};
      float sxx6[6];
#pragma unroll
      for(int k=0;k<6;k++) sxx6[k]=base[4*NPTS+i*6+k];
      float nsi[3]={base[10*NPTS+i*3+0], base[10*NPTS+i*3+1], base[10*NPTS+i*3+2]};
      float sn[3]={acc[s][0],acc[s][1],acc[s][2]};
      float sxn[3][3];
#pragma unroll
      for(int a=0;a<3;a++)
#pragma unroll
        for(int b=0;b<3;b++) sxn[a][b]=acc[s][3+a*3+b];
      const int m6[3][3]={{0,1,2},{1,3,4},{2,4,5}};
      float cxx[3][3], cxn[3][3];
#pragma unroll
      for(int a=0;a<3;a++)
#pragma unroll
        for(int b=0;b<3;b++){
          cxx[a][b]=sxx6[m6[a][b]] - v[a]*sx[b] - sx[a]*v[b] + s0*v[a]*v[b];
          cxn[a][b]=sxn[a][b]    - v[a]*sn[b] - sx[a]*nsi[b] + s0*v[a]*nsi[b];
        }
      float t1[3],t2[3];
      tangent(nsi[0],nsi[1],nsi[2],t1,t2);
      float ppt[2][2], pqt[2][2];
#pragma unroll
      for(int k=0;k<2;k++){
        const float* tk = (k==0)?t1:t2;
#pragma unroll
        for(int l=0;l<2;l++){
          const float* tl = (l==0)?t1:t2;
          float accx=0.0f, accn=0.0f;
#pragma unroll
          for(int a=0;a<3;a++)
#pragma unroll
            for(int b=0;b<3;b++){
              accx += tk[a]*cxx[a][b]*tl[b];
              accn += tk[a]*cxn[a][b]*tl[b];
            }
          ppt[k][l]=accx + ((k==l)?0.01f:0.0f);
          pqt[k][l]=accn;
        }
      }
      float det = ppt[0][0]*ppt[1][1]-ppt[0][1]*ppt[1][0];
      float id = 1.0f/det;
      float S00=( ppt[1][1]*pqt[0][0]-ppt[0][1]*pqt[1][0])*id;
      float S01=( ppt[1][1]*pqt[0][1]-ppt[0][1]*pqt[1][1])*id;
      float S10=(-ppt[1][0]*pqt[0][0]+ppt[0][0]*pqt[1][0])*id;
      float S11=(-ppt[1][0]*pqt[0][1]+ppt[0][0]*pqt[1][1])*id;
      float f0=fminf(fmaxf(S00+S11,-1.0f),1.0f);
      float f1=fminf(fmaxf(S00*S11-S01*S10,-1.0f),1.0f);
      xfF[i*DINF+16+2*s]=f0;
      xfF[i*DINF+17+2*s]=f1;
    }
  }
}

// ---- k3 ----
__global__ __launch_bounds__(256) void k3_mlps(const float* __restrict__ xfF,
    const float* os_w1, const float* os_b1, const float* os_w2, const float* os_b2,
    const float* ni_w1, const float* ni_b1, const float* ni_w2, const float* ni_b2,
    float* __restrict__ wOS, float* __restrict__ hPre, float* __restrict__ stats){
  int i = blockIdx.x*256 + threadIdx.x;
  int lane = threadIdx.x & 63;
  float xf[DINF];
#pragma unroll
  for(int k=0;k<DINF;k++) xf[k]=xfF[i*DINF+k];
  float h1[16];
#pragma unroll
  for(int o=0;o<16;o++){
    float t=ldb(os_b1,o);
#pragma unroll
    for(int k=0;k<DINF;k++) t += xf[k]*ldb(os_w1,o*DINF+k);
    h1[o]=lk(t);
  }
  float w=ldb(os_b2,0);
#pragma unroll
  for(int o=0;o<16;o++) w += h1[o]*ldb(os_w2,o);
  wOS[i]=w;
#pragma unroll
  for(int o=0;o<16;o++){
    float t=ldb(ni_b1,o);
#pragma unroll
    for(int k=0;k<DINF;k++) t += xf[k]*ldb(ni_w1,o*DINF+k);
    h1[o]=lk(t);
  }
  float h2[16];
#pragma unroll
  for(int o=0;o<16;o++){
    float t=ldb(ni_b2,o);
#pragma unroll
    for(int k=0;k<16;k++) t += h1[k]*ldb(ni_w2,o*16+k);
    h2[o]=lk(t);
    hPre[i*16+o]=h2[o];
  }
  float gs[4]={0,0,0,0}, gq[4]={0,0,0,0};
#pragma unroll
  for(int c=0;c<16;c++){ gs[c>>2]+=h2[c]; gq[c>>2]+=h2[c]*h2[c]; }
  __shared__ float ls[8];
  if(threadIdx.x<8) ls[threadIdx.x]=0.0f;
  __syncthreads();
#pragma unroll
  for(int g=0;g<4;g++){ gs[g]=wsum64(gs[g]); gq[g]=wsum64(gq[g]); }
  if(lane==0){
#pragma unroll
    for(int g=0;g<4;g++){ atomicAdd(&ls[2*g],gs[g]); atomicAdd(&ls[2*g+1],gq[g]); }
  }
  __syncthreads();
  if(threadIdx.x<8) atomicAdd(&stats[threadIdx.x], ls[threadIdx.x]);
}

// ---- k3c: GN -> bf16 transposed hTb[16][4096] ----
__global__ __launch_bounds__(256) void k3c_gn(const float* __restrict__ hPre,
                                              const float* __restrict__ stats,
                                              const float* gw, const float* gb,
                                              unsigned short* __restrict__ hTb){
  int i = blockIdx.x*256 + threadIdx.x;
  float m[4], r[4];
#pragma unroll
  for(int g=0;g<4;g++){
    float mean = stats[2*g]*(1.0f/(4.0f*NPTS));
    float var  = stats[2*g+1]*(1.0f/(4.0f*NPTS)) - mean*mean;
    m[g]=mean; r[g]=1.0f/sqrtf(var+1e-5f);
  }
#pragma unroll
  for(int c=0;c<16;c++){
    int g=c>>2;
    float v=(hPre[i*16+c]-m[g])*r[g]*ldb(gw,c)+ldb(gb,c);
    hTb[c*NPTS+i]=f2bf(v);
  }
}

// ---- k4 ----
__global__ __launch_bounds__(256) void k4_ov(const float* __restrict__ pF,
                                             const float* __restrict__ nF,
                                             const float* __restrict__ wOS,
                                             float* __restrict__ nuvF){
  int lane = threadIdx.x & 63;
  int i = blockIdx.x*4 + (threadIdx.x>>6);
  float pix=pF[i*3+0], piy=pF[i*3+1], piz=pF[i*3+2];
  float nix=nF[i*3+0], niy=nF[i*3+1], niz=nF[i*3+2];
  float a0=0,a1=0,a2=0,a3=0;
#pragma unroll 1
  for(int j=lane;j<NPTS;j+=64){
    float px=pF[j*3+0], py=pF[j*3+1], pz=pF[j*3+2];
    float nx=nF[j*3+0], ny=nF[j*3+1], nz=nF[j*3+2];
    float wj=wOS[j];
    float dx=px-pix, dy=py-piy, dz=pz-piz;
    float d2=dx*dx+dy*dy+dz*dz;
    float f=2.0f-(nx*nix+ny*niy+nz*niz);
    float Wv=__expf(-d2*f*f);
    float Ww=Wv*wj;
    a0+=Ww*px; a1+=Ww*py; a2+=Ww*pz; a3+=Ww;
  }
  a0=wsum64(a0); a1=wsum64(a1); a2=wsum64(a2); a3=wsum64(a3);
  if(lane==0){
    float o0=a0-a3*pix, o1=a1-a3*piy, o2=a2-a3*piz;
    float t1[3],t2[3];
    tangent(nix,niy,niz,t1,t2);
    float ov0=t1[0]*o0+t1[1]*o1+t1[2]*o2+1e-5f;
    float ov1=t2[0]*o0+t2[1]*o1+t2[2]*o2+1e-5f;
    float inv=1.0f/sqrtf(ov0*ov0+ov1*ov1);
    float ex=ov0*inv, ey=ov1*inv;
    nuvF[i*9+0]=nix; nuvF[i*9+1]=niy; nuvF[i*9+2]=niz;
    nuvF[i*9+3]= ex*t1[0]+ey*t2[0]; nuvF[i*9+4]= ex*t1[1]+ey*t2[1]; nuvF[i*9+5]= ex*t1[2]+ey*t2[2];
    nuvF[i*9+6]=-ey*t1[0]+ex*t2[0]; nuvF[i*9+7]=-ey*t1[1]+ex*t2[1]; nuvF[i*9+8]=-ey*t1[2]+ex*t2[2];
  }
}

// ---- k5: conv block via MFMA (race-fixed with block barriers) --------------
// Per wave: one i.  M[h][c] = sum_j hT[h][j] * z'[j][c]  via 16x16x32 bf16 MFMA
// z'[j][0..7]=win*relu(r_c), z'[j][8]=win, cols 9..15 zeroed.
// xi[i][h] = sum_c a2[h][c]*M[h][c] + b2[h]*M[h][8]
// LDS write (lane=j) -> read (other lanes' rows) is cross-lane communication:
// MUST be separated by __syncthreads() or the compiler may pipeline iterations
// (R3/R4 failure: first chunk correct, later chunks corrupted).
__global__ __launch_bounds__(256) void k5_conv(const float* __restrict__ pF,
                                               const float* __restrict__ nF,
                                               const float* __restrict__ nuvF,
                                               const unsigned short* __restrict__ hTb,
                                               const float* cv_a1, const float* cv_b1,
                                               const float* cv_a2, const float* cv_b2,
                                               float* __restrict__ xiF){
  __shared__ unsigned short zs[4][64][20];  // per-wave tile, row pad 20 (40B)
  int lane = threadIdx.x & 63;
  int w = threadIdx.x >> 6;
  int i = blockIdx.x*4 + w;
  int c16 = lane & 15, q = lane >> 4;
#pragma unroll
  for(int c=9;c<20;c++) zs[w][lane][c]=0;

  float pix=pF[i*3+0], piy=pF[i*3+1], piz=pF[i*3+2];
  float nu[9];
#pragma unroll
  for(int k=0;k<9;k++) nu[k]=nuvF[i*9+k];
  float a1w[8][3], b1w[8];
#pragma unroll
  for(int c=0;c<8;c++){
    a1w[c][0]=cv_a1[c*3+0]; a1w[c][1]=cv_a1[c*3+1]; a1w[c][2]=cv_a1[c*3+2];
    b1w[c]=cv_b1[c];
  }
  const unsigned short* hrow = hTb + c16*NPTS;  // A row m = lane&15
  f32x4v acc = {0.0f,0.0f,0.0f,0.0f};
  __syncthreads();

#pragma unroll 1
  for(int jb=0; jb<NPTS; jb+=64){
    // phase 1: lane = local j; compute z' row, store bf16 to LDS
    int j = jb + lane;
    float px=pF[j*3+0], py=pF[j*3+1], pz=pF[j*3+2];
    float nx=nF[j*3+0], ny=nF[j*3+1], nz=nF[j*3+2];
    float dx=px-pix, dy=py-piy, dz=pz-piz;
    float d2=dx*dx+dy*dy+dz*dz;
    float f=2.0f-(nx*nu[0]+ny*nu[1]+nz*nu[2]);
    float win=__expf(-d2*f*f);
    float X0=nu[0]*dx+nu[1]*dy+nu[2]*dz;
    float X1=nu[3]*dx+nu[4]*dy+nu[5]*dz;
    float X2=nu[6]*dx+nu[7]*dy+nu[8]*dz;
    unsigned short* zrow = &zs[w][lane][0];
#pragma unroll
    for(int c=0;c<8;c++){
      float r=fmaf(X0,a1w[c][0],fmaf(X1,a1w[c][1],fmaf(X2,a1w[c][2],b1w[c])));
      zrow[c]=f2bf(win*fmaxf(r,0.0f));
    }
    zrow[8]=f2bf(win);
    __syncthreads();   // writes visible before cross-lane reads
    // phase 2: two K=32 chunks -> MFMA
#pragma unroll
    for(int q2=0;q2<2;q2++){
      int jb2 = jb + q2*32;
      bf16x8v afr = *(const bf16x8v*)(hrow + jb2 + q*8);
      bf16x8v bfr;
#pragma unroll
      for(int t=0;t<8;t++){
        unsigned short v = zs[w][q2*32 + q*8 + t][c16];
        bfr[t] = __builtin_bit_cast(__bf16, v);
      }
      acc = __builtin_amdgcn_mfma_f32_16x16x32_bf16(afr, bfr, acc, 0, 0, 0);
    }
    __syncthreads();   // reads done before next iteration overwrites
  }
  // epilogue: C/D layout col=lane&15, row=q*4+reg (verified by R4 probe)
#pragma unroll
  for(int r=0;r<4;r++){
    int h = q*4 + r;
    float coef = (c16<8) ? cv_a2[h*8+c16] : ((c16==8) ? cv_b2[h] : 0.0f);
    float v = acc[r]*coef;
#pragma unroll
    for(int o=1;o<16;o<<=1) v += __shfl_xor(v,o);
    if(c16==0) xiF[i*16+h]=v;
  }
}

// ---- k6a ----
__global__ __launch_bounds__(256) void k6a(const float* __restrict__ xiF,
    const float* no_w1, const float* no_b1, const float* no_w2, const float* no_b2,
    float* __restrict__ tF, float* __restrict__ stats2){
  int i = blockIdx.x*256 + threadIdx.x;
  int lane = threadIdx.x & 63;
  float xi[16];
#pragma unroll
  for(int k=0;k<16;k++) xi[k]=xiF[i*16+k];
  float t1[16];
#pragma unroll
  for(int o=0;o<16;o++){
    float t=ldb(no_b1,o);
#pragma unroll
    for(int k=0;k<16;k++) t += xi[k]*ldb(no_w1,o*16+k);
    t1[o]=lk(t);
  }
  float t2[16];
#pragma unroll
  for(int o=0;o<16;o++){
    float t=ldb(no_b2,o);
#pragma unroll
    for(int k=0;k<16;k++) t += t1[k]*ldb(no_w2,o*16+k);
    t2[o]=lk(t);
    tF[i*16+o]=t2[o];
  }
  float gs[4]={0,0,0,0}, gq[4]={0,0,0,0};
#pragma unroll
  for(int c=0;c<16;c++){ gs[c>>2]+=t2[c]; gq[c>>2]+=t2[c]*t2[c]; }
  __shared__ float ls[8];
  if(threadIdx.x<8) ls[threadIdx.x]=0.0f;
  __syncthreads();
#pragma unroll
  for(int g=0;g<4;g++){ gs[g]=wsum64(gs[g]); gq[g]=wsum64(gq[g]); }
  if(lane==0){
#pragma unroll
    for(int g=0;g<4;g++){ atomicAdd(&ls[2*g],gs[g]); atomicAdd(&ls[2*g+1],gq[g]); }
  }
  __syncthreads();
  if(threadIdx.x<8) atomicAdd(&stats2[threadIdx.x], ls[threadIdx.x]);
}

// ---- k6c ----
__global__ __launch_bounds__(256) void k6c(const float* __restrict__ tF,
    const float* __restrict__ xfF, const float* __restrict__ stats2,
    const float* gw, const float* gb,
    const float* ll_w1, const float* ll_b1, const float* ll_w2, const float* ll_b2,
    const float* lt_w, const float* lt_b,
    float* __restrict__ out){
  int i = blockIdx.x*256 + threadIdx.x;
  float m[4], r[4];
#pragma unroll
  for(int g=0;g<4;g++){
    float mean = stats2[2*g]*(1.0f/(4.0f*NPTS));
    float var  = stats2[2*g+1]*(1.0f/(4.0f*NPTS)) - mean*mean;
    m[g]=mean; r[g]=1.0f/sqrtf(var+1e-5f);
  }
  float tn[16];
#pragma unroll
  for(int c=0;c<16;c++){
    int g=c>>2;
    tn[c]=(tF[i*16+c]-m[g])*r[g]*ldb(gw,c)+ldb(gb,c);
  }
  float z1[16];
#pragma unroll
  for(int o=0;o<16;o++){
    float t=ldb(ll_b1,o);
#pragma unroll
    for(int k=0;k<16;k++) t += tn[k]*ldb(ll_w1,o*16+k);
    z1[o]=fmaxf(t,0.0f);
  }
  float xf[DINF];
#pragma unroll
  for(int k=0;k<DINF;k++) xf[k]=xfF[i*DINF+k];
#pragma unroll
  for(int o=0;o<16;o++){
    float z=ldb(ll_b2,o);
#pragma unroll
    for(int k=0;k<16;k++) z += z1[k]*ldb(ll_w2,o*16+k);
    float lt=ldb(lt_b,o);
#pragma unroll
    for(int k=0;k<DINF;k++) lt += xf[k]*ldb(lt_w,o*DINF+k);
    out[i*16+o]=z+lt;
  }
}

extern "C" void kernel_launch(void* const* d_in, const int* in_sizes, int n_in,
                              void* d_out, int out_size, void* d_ws, size_t ws_size,
                              hipStream_t stream){
  const float* verts    = (const float*)d_in[0];
  const float* vnormals = (const float*)d_in[1];
  const float* x        = (const float*)d_in[2];
  const float* os_w1    = (const float*)d_in[3];
  const float* os_b1    = (const float*)d_in[4];
  const float* os_w2    = (const float*)d_in[5];
  const float* os_b2    = (const float*)d_in[6];
  const float* ni_w1    = (const float*)d_in[7];
  const float* ni_b1    = (const float*)d_in[8];
  const float* ni_w2    = (const float*)d_in[9];
  const float* ni_b2    = (const float*)d_in[10];
  const float* gn_in_w  = (const float*)d_in[11];
  const float* gn_in_b  = (const float*)d_in[12];
  const float* cv_a1    = (const float*)d_in[13];
  const float* cv_b1    = (const float*)d_in[14];
  const float* cv_a2    = (const float*)d_in[15];
  const float* cv_b2    = (const float*)d_in[16];
  const float* no_w1    = (const float*)d_in[17];
  const float* no_b1    = (const float*)d_in[18];
  const float* no_w2    = (const float*)d_in[19];
  const float* no_b2    = (const float*)d_in[20];
  const float* gn_out_w = (const float*)d_in[21];
  const float* gn_out_b = (const float*)d_in[22];
  const float* ll_w1    = (const float*)d_in[23];
  const float* ll_b1    = (const float*)d_in[24];
  const float* ll_w2    = (const float*)d_in[25];
  const float* ll_b2    = (const float*)d_in[26];
  const float* lt_w     = (const float*)d_in[27];
  const float* lt_b     = (const float*)d_in[28];

  float* W = (float*)d_ws;
  size_t off = 0;
  float* vertsF = W + off; off += (size_t)3*NPTS;
  float* nF     = W + off; off += (size_t)3*NPTS;
  float* pF     = W + off; off += (size_t)3*NPTS;
  float* xfF    = W + off; off += (size_t)DINF*NPTS;
  float* sc     = W + off; off += (size_t)13*NPTS*5;
  float* wOS    = W + off; off += (size_t)NPTS;
  float* hPre   = W + off; off += (size_t)16*NPTS;
  unsigned short* hTb = (unsigned short*)(W + off); off += (size_t)8*NPTS;
  float* nuvF   = W + off; off += (size_t)9*NPTS;
  float* xiF    = W + off; off += (size_t)16*NPTS;
  float* tF     = W + off; off += (size_t)16*NPTS;
  float* stats  = W + off; off += 16;

  hipMemsetAsync(stats, 0, 16*sizeof(float), stream);

  k0_convert<<<NPTS/256, 256, 0, stream>>>(verts, vnormals, x, vertsF, nF, pF, xfF);
  k1_pass1<<<NPTS/4, 256, 0, stream>>>(vertsF, nF, sc);
  k2_pass2<<<NPTS/4, 256, 0, stream>>>(vertsF, sc, xfF);
  k3_mlps<<<NPTS/256, 256, 0, stream>>>(xfF, os_w1, os_b1, os_w2, os_b2,
                                        ni_w1, ni_b1, ni_w2, ni_b2, wOS, hPre, stats);
  k3c_gn<<<NPTS/256, 256, 0, stream>>>(hPre, stats, gn_in_w, gn_in_b, hTb);
  k4_ov<<<NPTS/4, 256, 0, stream>>>(pF, nF, wOS, nuvF);
  k5_conv<<<NPTS/4, 256, 0, stream>>>(pF, nF, nuvF, hTb, cv_a1, cv_b1, cv_a2, cv_b2, xiF);
  k6a<<<NPTS/256, 256, 0, stream>>>(xiF, no_w1, no_b1, no_w2, no_b2, tF, stats+8);
  k6c<<<NPTS/256, 256, 0, stream>>>(tF, xfF, stats+8, gn_out_w, gn_out_b,
                                    ll_w1, ll_b1, ll_w2, ll_b2, lt_w, lt_b, (float*)d_out);
}

// Round 7
// 343.140 us; speedup vs baseline: 31.4673x; 1.1648x over previous
//
#include <hip/hip_runtime.h>
#include <hip/hip_bf16.h>
#include <math.h>

#define NPTS 4096
#define DINF 26
#define LOG2E 1.44269504088896f

typedef float f32x4v __attribute__((ext_vector_type(4)));
typedef __bf16 bf16x8v __attribute__((ext_vector_type(8)));

__device__ __forceinline__ float ldb(const float* p, int i){ return p[i]; }
__device__ __forceinline__ float lk(float v){ return v >= 0.0f ? v : 0.2f*v; }
__device__ __forceinline__ float wsum64(float v){
#pragma unroll
  for(int o=32;o>0;o>>=1) v += __shfl_down(v,o);
  return v;
}
__device__ __forceinline__ unsigned short f2bf(float f){
  return __builtin_bit_cast(unsigned short, __float2bfloat16(f));
}
__device__ __forceinline__ float bf2f(unsigned short u){
  return __bfloat162float(__builtin_bit_cast(__hip_bfloat16, u));
}
__device__ __forceinline__ unsigned pk2(float a, float b){
  return (unsigned)f2bf(a) | ((unsigned)f2bf(b)<<16);
}
// hi/lo split: col = hi + lo recovers ~16 mantissa bits through 2 MFMAs.
__device__ __forceinline__ void split2(float a, float b, unsigned& h, unsigned& l){
  unsigned short ah=f2bf(a), bh=f2bf(b);
  float ar = a - bf2f(ah), br = b - bf2f(bh);
  h = (unsigned)ah | ((unsigned)bh<<16);
  l = (unsigned)f2bf(ar) | ((unsigned)f2bf(br)<<16);
}
// intra-wave LDS write->read ordering (DS pipe is in-order per wave; stop
// compiler pipelining across the exchange — R3/R4 lesson).
__device__ __forceinline__ void wave_lds_fence(){
  __builtin_amdgcn_wave_barrier();
  __builtin_amdgcn_s_waitcnt(0xC07F);   // lgkmcnt(0)
  __builtin_amdgcn_wave_barrier();
}
__device__ __forceinline__ void tangent(float nx,float ny,float nz,float* t1,float* t2){
  float s = (nz >= 0.0f) ? 1.0f : -1.0f;
  float a = -1.0f/(s+nz);
  float b = nx*ny*a;
  t1[0]=1.0f+s*nx*nx*a; t1[1]=s*b; t1[2]=-s*nx;
  t2[0]=b; t2[1]=s+ny*ny*a; t2[2]=-ny;
}

// ---- k0 ----
__global__ __launch_bounds__(256) void k0_convert(const float* __restrict__ verts,
                                                  const float* __restrict__ vnorm,
                                                  const float* __restrict__ x,
                                                  float* __restrict__ vertsF,
                                                  float* __restrict__ nF,
                                                  float* __restrict__ pF,
                                                  float* __restrict__ xfF){
  int i = blockIdx.x*blockDim.x + threadIdx.x;
  if(i >= NPTS) return;
#pragma unroll
  for(int d=0;d<3;d++){
    float v = verts[i*3+d];
    vertsF[i*3+d]=v;
    pF[i*3+d]=v*(1.0f/9.0f);
    nF[i*3+d]=vnorm[i*3+d];
  }
#pragma unroll
  for(int c=0;c<16;c++) xfF[i*DINF+c]=x[i*16+c];
}

// ---- k1m: curvature pass 1 via MFMA + hi/lo B splitting --------------------
// Block: one 16-i tile, 8 waves x 512-j. D_s[i][c] = sum_j w_s(i,j)*F[j][c],
// F = [1, v(3), x⊗x(6), n(3)] stored as hi+lo bf16 tiles (cancellation fix).
// sc per scale: [0,N)=s0, [N,4N)=sx, [4N,10N)=sxx6, [10N,13N)=RAW un
__global__ __launch_bounds__(512) void k1m(const float* __restrict__ vertsF,
                                           const float* __restrict__ nF,
                                           float* __restrict__ sc){
  __shared__ unsigned short fbh[8][64][18];
  __shared__ unsigned short fbl[8][64][18];
  __shared__ float vq[8][64][4];
  __shared__ float red[8][16][16];
  const float c2e[5] = {0.5f*LOG2E, 0.125f*LOG2E, (1.0f/18.0f)*LOG2E,
                        0.02f*LOG2E, 0.005f*LOG2E};
  int lane = threadIdx.x & 63, w = threadIdx.x >> 6;
  int c16 = lane & 15, q = lane >> 4;
  int i0 = blockIdx.x*16;
  int ia = i0 + c16;
  float vix=vertsF[ia*3+0], viy=vertsF[ia*3+1], viz=vertsF[ia*3+2];
  float nsqi = vix*vix+viy*viy+viz*viz;
  f32x4v acc[5];
#pragma unroll
  for(int s=0;s<5;s++) acc[s] = (f32x4v){0.0f,0.0f,0.0f,0.0f};

#pragma unroll 1
  for(int jb = w*512; jb < (w+1)*512; jb += 64){
    int j = jb + lane;
    float vx=vertsF[j*3+0], vy=vertsF[j*3+1], vz=vertsF[j*3+2];
    float nx=nF[j*3+0], ny=nF[j*3+1], nz=nF[j*3+2];
    float nsq = vx*vx+vy*vy+vz*vz;
    unsigned* fh = (unsigned*)&fbh[w][lane][0];
    unsigned* fl = (unsigned*)&fbl[w][lane][0];
    unsigned h,l;
    split2(1.0f, vx, h,l);      fh[0]=h; fl[0]=l;
    split2(vy, vz, h,l);        fh[1]=h; fl[1]=l;
    split2(vx*vx, vx*vy, h,l);  fh[2]=h; fl[2]=l;
    split2(vx*vz, vy*vy, h,l);  fh[3]=h; fl[3]=l;
    split2(vy*vz, vz*vz, h,l);  fh[4]=h; fl[4]=l;
    split2(nx, ny, h,l);        fh[5]=h; fl[5]=l;
    split2(nz, 0.0f, h,l);      fh[6]=h; fl[6]=l;
    fh[7]=0u; fl[7]=0u; fh[8]=0u; fl[8]=0u;
    *(float4*)&vq[w][lane][0] = make_float4(vx,vy,vz,nsq);
    wave_lds_fence();
#pragma unroll
    for(int q2=0;q2<2;q2++){
      int rb = q2*32 + q*8;
      bf16x8v bh, bl;
#pragma unroll
      for(int t=0;t<8;t++){
        bh[t] = __builtin_bit_cast(__bf16, fbh[w][rb+t][c16]);
        bl[t] = __builtin_bit_cast(__bf16, fbl[w][rb+t][c16]);
      }
      bf16x8v af[5];
#pragma unroll
      for(int t=0;t<8;t++){
        float4 vv = *(const float4*)&vq[w][rb+t][0];
        float dot = vix*vv.x + viy*vv.y + viz*vv.z;
        float d2 = fmaxf(nsqi + vv.w - 2.0f*dot, 0.0f);
#pragma unroll
        for(int s=0;s<5;s++)
          af[s][t] = __builtin_bit_cast(__bf16, f2bf(exp2f(-d2*c2e[s])));
      }
#pragma unroll
      for(int s=0;s<5;s++){
        acc[s] = __builtin_amdgcn_mfma_f32_16x16x32_bf16(af[s], bh, acc[s], 0,0,0);
        acc[s] = __builtin_amdgcn_mfma_f32_16x16x32_bf16(af[s], bl, acc[s], 0,0,0);
      }
    }
    wave_lds_fence();
  }
  // 8-wave reduce, write moments
#pragma unroll
  for(int s=0;s<5;s++){
#pragma unroll
    for(int r=0;r<4;r++) red[w][q*4+r][c16] = acc[s][r];
    __syncthreads();
    if(w==0){
      float* base = sc + (size_t)s*13*NPTS;
#pragma unroll
      for(int r=0;r<4;r++){
        int m = q*4+r, i = i0+m;
        float D = 0.0f;
#pragma unroll
        for(int ww=0;ww<8;ww++) D += red[ww][m][c16];
        if(c16==0)       base[i]=D;
        else if(c16<4)   base[NPTS + i*3 + (c16-1)] = D;
        else if(c16<10)  base[4*NPTS + i*6 + (c16-4)] = D;
        else if(c16<13)  base[10*NPTS + i*3 + (c16-10)] = D;  // raw un
      }
    }
    __syncthreads();
  }
}

// ---- k2m: curvature pass 2 via MFMA (per-scale streamed hi/lo B) + solve ---
// D_s[i][c] = sum_j w_s(i,j) * F2_s[j][c],  F2_s = [ns_s(3), v⊗ns_s(9)]
__global__ __launch_bounds__(512) void k2m(const float* __restrict__ vertsF,
                                           float* __restrict__ sc,
                                           float* __restrict__ xfF){
  __shared__ unsigned short fbh[8][64][18];
  __shared__ unsigned short fbl[8][64][18];
  __shared__ float vq[8][64][4];
  __shared__ float red[8][16][16];
  const float c2e[5] = {0.5f*LOG2E, 0.125f*LOG2E, (1.0f/18.0f)*LOG2E,
                        0.02f*LOG2E, 0.005f*LOG2E};
  int lane = threadIdx.x & 63, w = threadIdx.x >> 6;
  int c16 = lane & 15, q = lane >> 4;
  int i0 = blockIdx.x*16;
  int ia = i0 + c16;
  float vix=vertsF[ia*3+0], viy=vertsF[ia*3+1], viz=vertsF[ia*3+2];
  float nsqi = vix*vix+viy*viy+viz*viz;
  f32x4v acc[5];
#pragma unroll
  for(int s=0;s<5;s++) acc[s] = (f32x4v){0.0f,0.0f,0.0f,0.0f};

#pragma unroll 1
  for(int jb = w*512; jb < (w+1)*512; jb += 64){
    int j = jb + lane;
    float vx=vertsF[j*3+0], vy=vertsF[j*3+1], vz=vertsF[j*3+2];
    float nsq = vx*vx+vy*vy+vz*vz;
    *(float4*)&vq[w][lane][0] = make_float4(vx,vy,vz,nsq);
    wave_lds_fence();
    float d2c[2][8];
#pragma unroll
    for(int q2=0;q2<2;q2++)
#pragma unroll
      for(int t=0;t<8;t++){
        float4 vv = *(const float4*)&vq[w][q2*32+q*8+t][0];
        float dot = vix*vv.x + viy*vv.y + viz*vv.z;
        d2c[q2][t] = fmaxf(nsqi + vv.w - 2.0f*dot, 0.0f);
      }
#pragma unroll
    for(int s=0;s<5;s++){
      const float* ub = sc + (size_t)s*13*NPTS + 10*NPTS + (size_t)j*3;
      float ux=ub[0], uy=ub[1], uz=ub[2];
      float inv = 1.0f/fmaxf(sqrtf(ux*ux+uy*uy+uz*uz), 1e-12f);
      float n0=ux*inv, n1=uy*inv, n2=uz*inv;
      unsigned* fh = (unsigned*)&fbh[w][lane][0];
      unsigned* fl = (unsigned*)&fbl[w][lane][0];
      unsigned h,l;
      split2(n0, n1, h,l);        fh[0]=h; fl[0]=l;
      split2(n2, vx*n0, h,l);     fh[1]=h; fl[1]=l;
      split2(vx*n1, vx*n2, h,l);  fh[2]=h; fl[2]=l;
      split2(vy*n0, vy*n1, h,l);  fh[3]=h; fl[3]=l;
      split2(vy*n2, vz*n0, h,l);  fh[4]=h; fl[4]=l;
      split2(vz*n1, vz*n2, h,l);  fh[5]=h; fl[5]=l;
      fh[6]=0u; fl[6]=0u; fh[7]=0u; fl[7]=0u; fh[8]=0u; fl[8]=0u;
      wave_lds_fence();
#pragma unroll
      for(int q2=0;q2<2;q2++){
        int rb = q2*32 + q*8;
        bf16x8v af, bh, bl;
#pragma unroll
        for(int t=0;t<8;t++){
          af[t] = __builtin_bit_cast(__bf16, f2bf(exp2f(-d2c[q2][t]*c2e[s])));
          bh[t] = __builtin_bit_cast(__bf16, fbh[w][rb+t][c16]);
          bl[t] = __builtin_bit_cast(__bf16, fbl[w][rb+t][c16]);
        }
        acc[s] = __builtin_amdgcn_mfma_f32_16x16x32_bf16(af, bh, acc[s], 0,0,0);
        acc[s] = __builtin_amdgcn_mfma_f32_16x16x32_bf16(af, bl, acc[s], 0,0,0);
      }
      wave_lds_fence();
    }
  }
  // reduce + curvature solve
#pragma unroll
  for(int s=0;s<5;s++){
#pragma unroll
    for(int r=0;r<4;r++) red[w][q*4+r][c16] = acc[s][r];
    __syncthreads();
    if(w==0){
#pragma unroll
      for(int r=0;r<4;r++){
        int m = q*4+r;
        float D = 0.0f;
#pragma unroll
        for(int ww=0;ww<8;ww++) D += red[ww][m][c16];
        red[0][m][c16] = D;
      }
    }
    __syncthreads();
    if(threadIdx.x < 16){
      int tid = threadIdx.x, i = i0 + tid;
      const float* base = sc + (size_t)s*13*NPTS;
      float v[3] = { vertsF[i*3+0], vertsF[i*3+1], vertsF[i*3+2] };
      float s0 = base[i];
      float sx[3] = { base[NPTS+i*3+0], base[NPTS+i*3+1], base[NPTS+i*3+2] };
      float sxx6[6];
#pragma unroll
      for(int k=0;k<6;k++) sxx6[k]=base[4*NPTS+i*6+k];
      float ux=base[10*NPTS+i*3+0], uy=base[10*NPTS+i*3+1], uz=base[10*NPTS+i*3+2];
      float invn = 1.0f/fmaxf(sqrtf(ux*ux+uy*uy+uz*uz), 1e-12f);
      float nsi[3] = { ux*invn, uy*invn, uz*invn };
      float sn[3] = { red[0][tid][0], red[0][tid][1], red[0][tid][2] };
      float sxn[3][3];
#pragma unroll
      for(int a=0;a<3;a++)
#pragma unroll
        for(int b=0;b<3;b++) sxn[a][b]=red[0][tid][3+a*3+b];
      const int m6[3][3]={{0,1,2},{1,3,4},{2,4,5}};
      float cxx[3][3], cxn[3][3];
#pragma unroll
      for(int a=0;a<3;a++)
#pragma unroll
        for(int b=0;b<3;b++){
          cxx[a][b]=sxx6[m6[a][b]] - v[a]*sx[b] - sx[a]*v[b] + s0*v[a]*v[b];
          cxn[a][b]=sxn[a][b]    - v[a]*sn[b] - sx[a]*nsi[b] + s0*v[a]*nsi[b];
        }
      float t1[3],t2[3];
      tangent(nsi[0],nsi[1],nsi[2],t1,t2);
      float ppt[2][2], pqt[2][2];
#pragma unroll
      for(int k=0;k<2;k++){
        const float* tk = (k==0)?t1:t2;
#pragma unroll
        for(int l=0;l<2;l++){
          const float* tl = (l==0)?t1:t2;
          float accx=0.0f, accn=0.0f;
#pragma unroll
          for(int a=0;a<3;a++)
#pragma unroll
            for(int b=0;b<3;b++){
              accx += tk[a]*cxx[a][b]*tl[b];
              accn += tk[a]*cxn[a][b]*tl[b];
            }
          ppt[k][l]=accx + ((k==l)?0.01f:0.0f);
          pqt[k][l]=accn;
        }
      }
      float det = ppt[0][0]*ppt[1][1]-ppt[0][1]*ppt[1][0];
      float id = 1.0f/det;
      float S00=( ppt[1][1]*pqt[0][0]-ppt[0][1]*pqt[1][0])*id;
      float S01=( ppt[1][1]*pqt[0][1]-ppt[0][1]*pqt[1][1])*id;
      float S10=(-ppt[1][0]*pqt[0][0]+ppt[0][0]*pqt[1][0])*id;
      float S11=(-ppt[1][0]*pqt[0][1]+ppt[0][0]*pqt[1][1])*id;
      float f0=fminf(fmaxf(S00+S11,-1.0f),1.0f);
      float f1=fminf(fmaxf(S00*S11-S01*S10,-1.0f),1.0f);
      xfF[i*DINF+16+2*s]=f0;
      xfF[i*DINF+17+2*s]=f1;
    }
    __syncthreads();
  }
}

// ---- k3 ----
__global__ __launch_bounds__(256) void k3_mlps(const float* __restrict__ xfF,
    const float* os_w1, const float* os_b1, const float* os_w2, const float* os_b2,
    const float* ni_w1, const float* ni_b1, const float* ni_w2, const float* ni_b2,
    float* __restrict__ wOS, float* __restrict__ hPre, float* __restrict__ stats){
  int i = blockIdx.x*256 + threadIdx.x;
  int lane = threadIdx.x & 63;
  float xf[DINF];
#pragma unroll
  for(int k=0;k<DINF;k++) xf[k]=xfF[i*DINF+k];
  float h1[16];
#pragma unroll
  for(int o=0;o<16;o++){
    float t=ldb(os_b1,o);
#pragma unroll
    for(int k=0;k<DINF;k++) t += xf[k]*ldb(os_w1,o*DINF+k);
    h1[o]=lk(t);
  }
  float w=ldb(os_b2,0);
#pragma unroll
  for(int o=0;o<16;o++) w += h1[o]*ldb(os_w2,o);
  wOS[i]=w;
#pragma unroll
  for(int o=0;o<16;o++){
    float t=ldb(ni_b1,o);
#pragma unroll
    for(int k=0;k<DINF;k++) t += xf[k]*ldb(ni_w1,o*DINF+k);
    h1[o]=lk(t);
  }
  float h2[16];
#pragma unroll
  for(int o=0;o<16;o++){
    float t=ldb(ni_b2,o);
#pragma unroll
    for(int k=0;k<16;k++) t += h1[k]*ldb(ni_w2,o*16+k);
    h2[o]=lk(t);
    hPre[i*16+o]=h2[o];
  }
  float gs[4]={0,0,0,0}, gq[4]={0,0,0,0};
#pragma unroll
  for(int c=0;c<16;c++){ gs[c>>2]+=h2[c]; gq[c>>2]+=h2[c]*h2[c]; }
  __shared__ float ls[8];
  if(threadIdx.x<8) ls[threadIdx.x]=0.0f;
  __syncthreads();
#pragma unroll
  for(int g=0;g<4;g++){ gs[g]=wsum64(gs[g]); gq[g]=wsum64(gq[g]); }
  if(lane==0){
#pragma unroll
    for(int g=0;g<4;g++){ atomicAdd(&ls[2*g],gs[g]); atomicAdd(&ls[2*g+1],gq[g]); }
  }
  __syncthreads();
  if(threadIdx.x<8) atomicAdd(&stats[threadIdx.x], ls[threadIdx.x]);
}

// ---- k3c: GN -> bf16 transposed hTb[16][4096] ----
__global__ __launch_bounds__(256) void k3c_gn(const float* __restrict__ hPre,
                                              const float* __restrict__ stats,
                                              const float* gw, const float* gb,
                                              unsigned short* __restrict__ hTb){
  int i = blockIdx.x*256 + threadIdx.x;
  float m[4], r[4];
#pragma unroll
  for(int g=0;g<4;g++){
    float mean = stats[2*g]*(1.0f/(4.0f*NPTS));
    float var  = stats[2*g+1]*(1.0f/(4.0f*NPTS)) - mean*mean;
    m[g]=mean; r[g]=1.0f/sqrtf(var+1e-5f);
  }
#pragma unroll
  for(int c=0;c<16;c++){
    int g=c>>2;
    float v=(hPre[i*16+c]-m[g])*r[g]*ldb(gw,c)+ldb(gb,c);
    hTb[c*NPTS+i]=f2bf(v);
  }
}

// ---- k4 ----
__global__ __launch_bounds__(256) void k4_ov(const float* __restrict__ pF,
                                             const float* __restrict__ nF,
                                             const float* __restrict__ wOS,
                                             float* __restrict__ nuvF){
  int lane = threadIdx.x & 63;
  int i = blockIdx.x*4 + (threadIdx.x>>6);
  float pix=pF[i*3+0], piy=pF[i*3+1], piz=pF[i*3+2];
  float nix=nF[i*3+0], niy=nF[i*3+1], niz=nF[i*3+2];
  float a0=0,a1=0,a2=0,a3=0;
#pragma unroll 1
  for(int j=lane;j<NPTS;j+=64){
    float px=pF[j*3+0], py=pF[j*3+1], pz=pF[j*3+2];
    float nx=nF[j*3+0], ny=nF[j*3+1], nz=nF[j*3+2];
    float wj=wOS[j];
    float dx=px-pix, dy=py-piy, dz=pz-piz;
    float d2=dx*dx+dy*dy+dz*dz;
    float f=2.0f-(nx*nix+ny*niy+nz*niz);
    float Wv=__expf(-d2*f*f);
    float Ww=Wv*wj;
    a0+=Ww*px; a1+=Ww*py; a2+=Ww*pz; a3+=Ww;
  }
  a0=wsum64(a0); a1=wsum64(a1); a2=wsum64(a2); a3=wsum64(a3);
  if(lane==0){
    float o0=a0-a3*pix, o1=a1-a3*piy, o2=a2-a3*piz;
    float t1[3],t2[3];
    tangent(nix,niy,niz,t1,t2);
    float ov0=t1[0]*o0+t1[1]*o1+t1[2]*o2+1e-5f;
    float ov1=t2[0]*o0+t2[1]*o1+t2[2]*o2+1e-5f;
    float inv=1.0f/sqrtf(ov0*ov0+ov1*ov1);
    float ex=ov0*inv, ey=ov1*inv;
    nuvF[i*9+0]=nix; nuvF[i*9+1]=niy; nuvF[i*9+2]=niz;
    nuvF[i*9+3]= ex*t1[0]+ey*t2[0]; nuvF[i*9+4]= ex*t1[1]+ey*t2[1]; nuvF[i*9+5]= ex*t1[2]+ey*t2[2];
    nuvF[i*9+6]=-ey*t1[0]+ex*t2[0]; nuvF[i*9+7]=-ey*t1[1]+ex*t2[1]; nuvF[i*9+8]=-ey*t1[2]+ex*t2[2];
  }
}

// ---- k5: conv via MFMA, wave-local exchange ------------------------------
__global__ __launch_bounds__(256) void k5_conv(const float* __restrict__ pF,
                                               const float* __restrict__ nF,
                                               const float* __restrict__ nuvF,
                                               const unsigned short* __restrict__ hTb,
                                               const float* cv_a1, const float* cv_b1,
                                               const float* cv_a2, const float* cv_b2,
                                               float* __restrict__ xiF){
  __shared__ unsigned short zs[4][64][18];
  int lane = threadIdx.x & 63;
  int w = threadIdx.x >> 6;
  int i = blockIdx.x*4 + w;
  int c16 = lane & 15, q = lane >> 4;
  unsigned* zr = (unsigned*)&zs[w][lane][0];
#pragma unroll
  for(int c=0;c<9;c++) zr[c]=0u;

  float pix=pF[i*3+0], piy=pF[i*3+1], piz=pF[i*3+2];
  float nu[9];
#pragma unroll
  for(int k=0;k<9;k++) nu[k]=nuvF[i*9+k];
  float a1w[8][3], b1w[8];
#pragma unroll
  for(int c=0;c<8;c++){
    a1w[c][0]=cv_a1[c*3+0]; a1w[c][1]=cv_a1[c*3+1]; a1w[c][2]=cv_a1[c*3+2];
    b1w[c]=cv_b1[c];
  }
  const unsigned short* hrow = hTb + c16*NPTS;
  f32x4v acc = {0.0f,0.0f,0.0f,0.0f};
  wave_lds_fence();

#pragma unroll 1
  for(int jb=0; jb<NPTS; jb+=64){
    int j = jb + lane;
    float px=pF[j*3+0], py=pF[j*3+1], pz=pF[j*3+2];
    float nx=nF[j*3+0], ny=nF[j*3+1], nz=nF[j*3+2];
    float dx=px-pix, dy=py-piy, dz=pz-piz;
    float d2=dx*dx+dy*dy+dz*dz;
    float f=2.0f-(nx*nu[0]+ny*nu[1]+nz*nu[2]);
    float win=__expf(-d2*f*f);
    float X0=nu[0]*dx+nu[1]*dy+nu[2]*dz;
    float X1=nu[3]*dx+nu[4]*dy+nu[5]*dz;
    float X2=nu[6]*dx+nu[7]*dy+nu[8]*dz;
    float z[8];
#pragma unroll
    for(int c=0;c<8;c++){
      float r=fmaf(X0,a1w[c][0],fmaf(X1,a1w[c][1],fmaf(X2,a1w[c][2],b1w[c])));
      z[c]=win*fmaxf(r,0.0f);
    }
    zr[0]=pk2(z[0],z[1]); zr[1]=pk2(z[2],z[3]);
    zr[2]=pk2(z[4],z[5]); zr[3]=pk2(z[6],z[7]);
    zr[4]=(unsigned)f2bf(win);
    wave_lds_fence();
#pragma unroll
    for(int q2=0;q2<2;q2++){
      int jb2 = jb + q2*32;
      bf16x8v afr = *(const bf16x8v*)(hrow + jb2 + q*8);
      bf16x8v bfr;
#pragma unroll
      for(int t=0;t<8;t++)
        bfr[t] = __builtin_bit_cast(__bf16, zs[w][q2*32 + q*8 + t][c16]);
      acc = __builtin_amdgcn_mfma_f32_16x16x32_bf16(afr, bfr, acc, 0, 0, 0);
    }
    wave_lds_fence();
  }
#pragma unroll
  for(int r=0;r<4;r++){
    int h = q*4 + r;
    float coef = (c16<8) ? cv_a2[h*8+c16] : ((c16==8) ? cv_b2[h] : 0.0f);
    float v = acc[r]*coef;
#pragma unroll
    for(int o=1;o<16;o<<=1) v += __shfl_xor(v,o);
    if(c16==0) xiF[i*16+h]=v;
  }
}

// ---- k6a ----
__global__ __launch_bounds__(256) void k6a(const float* __restrict__ xiF,
    const float* no_w1, const float* no_b1, const float* no_w2, const float* no_b2,
    float* __restrict__ tF, float* __restrict__ stats2){
  int i = blockIdx.x*256 + threadIdx.x;
  int lane = threadIdx.x & 63;
  float xi[16];
#pragma unroll
  for(int k=0;k<16;k++) xi[k]=xiF[i*16+k];
  float t1[16];
#pragma unroll
  for(int o=0;o<16;o++){
    float t=ldb(no_b1,o);
#pragma unroll
    for(int k=0;k<16;k++) t += xi[k]*ldb(no_w1,o*16+k);
    t1[o]=lk(t);
  }
  float t2[16];
#pragma unroll
  for(int o=0;o<16;o++){
    float t=ldb(no_b2,o);
#pragma unroll
    for(int k=0;k<16;k++) t += t1[k]*ldb(no_w2,o*16+k);
    t2[o]=lk(t);
    tF[i*16+o]=t2[o];
  }
  float gs[4]={0,0,0,0}, gq[4]={0,0,0,0};
#pragma unroll
  for(int c=0;c<16;c++){ gs[c>>2]+=t2[c]; gq[c>>2]+=t2[c]*t2[c]; }
  __shared__ float ls[8];
  if(threadIdx.x<8) ls[threadIdx.x]=0.0f;
  __syncthreads();
#pragma unroll
  for(int g=0;g<4;g++){ gs[g]=wsum64(gs[g]); gq[g]=wsum64(gq[g]); }
  if(lane==0){
#pragma unroll
    for(int g=0;g<4;g++){ atomicAdd(&ls[2*g],gs[g]); atomicAdd(&ls[2*g+1],gq[g]); }
  }
  __syncthreads();
  if(threadIdx.x<8) atomicAdd(&stats2[threadIdx.x], ls[threadIdx.x]);
}

// ---- k6c ----
__global__ __launch_bounds__(256) void k6c(const float* __restrict__ tF,
    const float* __restrict__ xfF, const float* __restrict__ stats2,
    const float* gw, const float* gb,
    const float* ll_w1, const float* ll_b1, const float* ll_w2, const float* ll_b2,
    const float* lt_w, const float* lt_b,
    float* __restrict__ out){
  int i = blockIdx.x*256 + threadIdx.x;
  float m[4], r[4];
#pragma unroll
  for(int g=0;g<4;g++){
    float mean = stats2[2*g]*(1.0f/(4.0f*NPTS));
    float var  = stats2[2*g+1]*(1.0f/(4.0f*NPTS)) - mean*mean;
    m[g]=mean; r[g]=1.0f/sqrtf(var+1e-5f);
  }
  float tn[16];
#pragma unroll
  for(int c=0;c<16;c++){
    int g=c>>2;
    tn[c]=(tF[i*16+c]-m[g])*r[g]*ldb(gw,c)+ldb(gb,c);
  }
  float z1[16];
#pragma unroll
  for(int o=0;o<16;o++){
    float t=ldb(ll_b1,o);
#pragma unroll
    for(int k=0;k<16;k++) t += tn[k]*ldb(ll_w1,o*16+k);
    z1[o]=fmaxf(t,0.0f);
  }
  float xf[DINF];
#pragma unroll
  for(int k=0;k<DINF;k++) xf[k]=xfF[i*DINF+k];
#pragma unroll
  for(int o=0;o<16;o++){
    float z=ldb(ll_b2,o);
#pragma unroll
    for(int k=0;k<16;k++) z += z1[k]*ldb(ll_w2,o*16+k);
    float lt=ldb(lt_b,o);
#pragma unroll
    for(int k=0;k<DINF;k++) lt += xf[k]*ldb(lt_w,o*DINF+k);
    out[i*16+o]=z+lt;
  }
}

extern "C" void kernel_launch(void* const* d_in, const int* in_sizes, int n_in,
                              void* d_out, int out_size, void* d_ws, size_t ws_size,
                              hipStream_t stream){
  const float* verts    = (const float*)d_in[0];
  const float* vnormals = (const float*)d_in[1];
  const float* x        = (const float*)d_in[2];
  const float* os_w1    = (const float*)d_in[3];
  const float* os_b1    = (const float*)d_in[4];
  const float* os_w2    = (const float*)d_in[5];
  const float* os_b2    = (const float*)d_in[6];
  const float* ni_w1    = (const float*)d_in[7];
  const float* ni_b1    = (const float*)d_in[8];
  const float* ni_w2    = (const float*)d_in[9];
  const float* ni_b2    = (const float*)d_in[10];
  const float* gn_in_w  = (const float*)d_in[11];
  const float* gn_in_b  = (const float*)d_in[12];
  const float* cv_a1    = (const float*)d_in[13];
  const float* cv_b1    = (const float*)d_in[14];
  const float* cv_a2    = (const float*)d_in[15];
  const float* cv_b2    = (const float*)d_in[16];
  const float* no_w1    = (const float*)d_in[17];
  const float* no_b1    = (const float*)d_in[18];
  const float* no_w2    = (const float*)d_in[19];
  const float* no_b2    = (const float*)d_in[20];
  const float* gn_out_w = (const float*)d_in[21];
  const float* gn_out_b = (const float*)d_in[22];
  const float* ll_w1    = (const float*)d_in[23];
  const float* ll_b1    = (const float*)d_in[24];
  const float* ll_w2    = (const float*)d_in[25];
  const float* ll_b2    = (const float*)d_in[26];
  const float* lt_w     = (const float*)d_in[27];
  const float* lt_b     = (const float*)d_in[28];

  float* W = (float*)d_ws;
  size_t off = 0;
  float* vertsF = W + off; off += (size_t)3*NPTS;
  float* nF     = W + off; off += (size_t)3*NPTS;
  float* pF     = W + off; off += (size_t)3*NPTS;
  float* xfF    = W + off; off += (size_t)DINF*NPTS;
  float* sc     = W + off; off += (size_t)13*NPTS*5;
  float* wOS    = W + off; off += (size_t)NPTS;
  float* hPre   = W + off; off += (size_t)16*NPTS;
  unsigned short* hTb = (unsigned short*)(W + off); off += (size_t)8*NPTS;
  float* nuvF   = W + off; off += (size_t)9*NPTS;
  float* xiF    = W + off; off += (size_t)16*NPTS;
  float* tF     = W + off; off += (size_t)16*NPTS;
  float* stats  = W + off; off += 16;

  hipMemsetAsync(stats, 0, 16*sizeof(float), stream);

  k0_convert<<<NPTS/256, 256, 0, stream>>>(verts, vnormals, x, vertsF, nF, pF, xfF);
  k1m<<<NPTS/16, 512, 0, stream>>>(vertsF, nF, sc);
  k2m<<<NPTS/16, 512, 0, stream>>>(vertsF, sc, xfF);
  k3_mlps<<<NPTS/256, 256, 0, stream>>>(xfF, os_w1, os_b1, os_w2, os_b2,
                                        ni_w1, ni_b1, ni_w2, ni_b2, wOS, hPre, stats);
  k3c_gn<<<NPTS/256, 256, 0, stream>>>(hPre, stats, gn_in_w, gn_in_b, hTb);
  k4_ov<<<NPTS/4, 256, 0, stream>>>(pF, nF, wOS, nuvF);
  k5_conv<<<NPTS/4, 256, 0, stream>>>(pF, nF, nuvF, hTb, cv_a1, cv_b1, cv_a2, cv_b2, xiF);
  k6a<<<NPTS/256, 256, 0, stream>>>(xiF, no_w1, no_b1, no_w2, no_b2, tF, stats+8);
  k6c<<<NPTS/256, 256, 0, stream>>>(tF, xfF, stats+8, gn_out_w, gn_out_b,
                                    ll_w1, ll_b1, ll_w2, ll_b2, lt_w, lt_b, (float*)d_out);
}